// Round 12
// baseline (109.124 us; speedup 1.0000x reference)
//
#include <hip/hip_runtime.h>
#include <math.h>

// PQC autoencoder. out = g(U x), U = fixed 256x256 unitary from thetas
// (input normalization cancels: y/||y|| scale-invariant in x).
// Kernel A (build_u, ~2 us): fused-gate statevector sim -> V = [Re U; Im U]
//   as RNE f16 in MFMA-B-fragment stream order (validated R10/R11).
// Kernel B (pqc_main): single-term f16 MFMA GEMM (32768 x 512 x 256).
//   R12: 4 blocks/CU (32 rows/block, 256 thr, grid 1024) — the only lever
//   that has moved time since R4 was block granularity (R7->R8, 1->2
//   blocks/CU, -5us). Wave owns full w-slice (re+im tt=0..7, mt=0..1),
//   acc = 64 AGPR; R7 conflict-free staging; DPP Walsh epilogue.

#define DEV __device__ __forceinline__

typedef __attribute__((ext_vector_type(8))) _Float16 half8;  // 8 f16 = 4 VGPR
typedef __attribute__((ext_vector_type(4))) float f32x4;

DEV float2 cmul(float2 a, float2 b) {
  return make_float2(a.x * b.x - a.y * b.y, a.x * b.y + a.y * b.x);
}
DEV float2 cadd(float2 a, float2 b) { return make_float2(a.x + b.x, a.y + b.y); }

DEV unsigned short f16b(float v) {
  _Float16 h = (_Float16)v;                    // RNE convert
  return __builtin_bit_cast(unsigned short, h);
}

// ---- DPP cross-lane (VALU pipe, rows of 16) ------------------------------
template <int CTRL>
DEV float dppf(float v) {
  return __int_as_float(__builtin_amdgcn_mov_dpp(__float_as_int(v), CTRL, 0xF, 0xF, true));
}
DEV float px1(float v) { return dppf<0xB1>(v); }                  // lane^1
DEV float px2(float v) { return dppf<0x4E>(v); }                  // lane^2
DEV float px4(float v) { return dppf<0x1B>(dppf<0x141>(v)); }     // ^7 then ^3 = ^4
DEV float px8(float v) { return dppf<0x141>(dppf<0x140>(v)); }    // ^15 then ^7 = ^8
DEV float fsgn(float v, int m) { return __int_as_float(__float_as_int(v) ^ m); }

// ---------------------------------------------------------------------------
// Kernel A (gate math unchanged, validated R2-R11)
// ---------------------------------------------------------------------------

struct Psi4 { float re[4]; float im[4]; };
// amplitude a = (r<<6)|lane; bit q of a: q<6 -> lane bit q; q==6 -> r&1; q==7 -> r>>1

template <int Q>
DEV void pair_gate(Psi4& s, const float2* __restrict__ Mlo,
                   const float2* __restrict__ Mhi, int lane) {
  const int b0 = (lane >> Q) & 1, b1 = (lane >> (Q + 1)) & 1;
  float2 lo_d = Mlo[b0 * 2 + b0];
  float2 lo_o = Mlo[b0 * 2 + (b0 ^ 1)];
  float2 hi_d = Mhi[b1 * 2 + b1];
  float2 hi_o = Mhi[b1 * 2 + (b1 ^ 1)];
  float2 c00 = cmul(hi_d, lo_d);
  float2 c01 = cmul(hi_d, lo_o);
  float2 c10 = cmul(hi_o, lo_d);
  float2 c11 = cmul(hi_o, lo_o);
  const int m0 = 1 << Q, m1 = 2 << Q;
#pragma unroll
  for (int r = 0; r < 4; ++r) {
    float ar = s.re[r], ai = s.im[r];
    float p0r = __shfl_xor(ar, m0, 64), p0i = __shfl_xor(ai, m0, 64);
    float p1r = __shfl_xor(ar, m1, 64), p1i = __shfl_xor(ai, m1, 64);
    float p2r = __shfl_xor(ar, m0 | m1, 64), p2i = __shfl_xor(ai, m0 | m1, 64);
    float nr = c00.x * ar - c00.y * ai + c01.x * p0r - c01.y * p0i
             + c10.x * p1r - c10.y * p1i + c11.x * p2r - c11.y * p2i;
    float ni = c00.x * ai + c00.y * ar + c01.x * p0i + c01.y * p0r
             + c10.x * p1i + c10.y * p1r + c11.x * p2i + c11.y * p2r;
    s.re[r] = nr; s.im[r] = ni;
  }
}

DEV void regpair_gate(Psi4& s, const float2* __restrict__ Mlo,
                      const float2* __restrict__ Mhi) {
  float nr[4], ni[4];
#pragma unroll
  for (int r = 0; r < 4; ++r) {
    const int b0 = r & 1, b1 = (r >> 1) & 1;
    float2 c00 = cmul(Mhi[b1 * 2 + b1], Mlo[b0 * 2 + b0]);
    float2 c01 = cmul(Mhi[b1 * 2 + b1], Mlo[b0 * 2 + (b0 ^ 1)]);
    float2 c10 = cmul(Mhi[b1 * 2 + (b1 ^ 1)], Mlo[b0 * 2 + b0]);
    float2 c11 = cmul(Mhi[b1 * 2 + (b1 ^ 1)], Mlo[b0 * 2 + (b0 ^ 1)]);
    nr[r] = c00.x * s.re[r] - c00.y * s.im[r]
          + c01.x * s.re[r ^ 1] - c01.y * s.im[r ^ 1]
          + c10.x * s.re[r ^ 2] - c10.y * s.im[r ^ 2]
          + c11.x * s.re[r ^ 3] - c11.y * s.im[r ^ 3];
    ni[r] = c00.x * s.im[r] + c00.y * s.re[r]
          + c01.x * s.im[r ^ 1] + c01.y * s.re[r ^ 1]
          + c10.x * s.im[r ^ 2] + c10.y * s.re[r ^ 2]
          + c11.x * s.im[r ^ 3] + c11.y * s.re[r ^ 3];
  }
#pragma unroll
  for (int r = 0; r < 4; ++r) { s.re[r] = nr[r]; s.im[r] = ni[r]; }
}

DEV void reg0_gate(Psi4& s, const float2* __restrict__ M) {
  float nr[4], ni[4];
#pragma unroll
  for (int r = 0; r < 4; ++r) {
    const int b = r & 1;
    float2 d = M[b * 2 + b], o = M[b * 2 + (b ^ 1)];
    nr[r] = d.x * s.re[r] - d.y * s.im[r] + o.x * s.re[r ^ 1] - o.y * s.im[r ^ 1];
    ni[r] = d.x * s.im[r] + d.y * s.re[r] + o.x * s.im[r ^ 1] + o.y * s.re[r ^ 1];
  }
#pragma unroll
  for (int r = 0; r < 4; ++r) { s.re[r] = nr[r]; s.im[r] = ni[r]; }
}

template <bool FULL8>
DEV void perm_cx(Psi4& s, int lane) {
  const int slane = (lane ^ (lane << 1)) & 63;
  const bool L5 = ((lane >> 5) & 1) != 0;
  float nr[4], ni[4];
#pragma unroll
  for (int r = 0; r < 4; ++r) {
    const int r0 = r & 1, r1 = (r >> 1) & 1;
    const int hiBit = FULL8 ? (r1 ^ r0) : r1;
    const int sA = (hiBit << 1) | r0;
    const int sB = sA ^ 1;
    float aRe = __shfl(s.re[sA], slane, 64);
    float aIm = __shfl(s.im[sA], slane, 64);
    float bRe = __shfl(s.re[sB], slane, 64);
    float bIm = __shfl(s.im[sB], slane, 64);
    nr[r] = L5 ? bRe : aRe;
    ni[r] = L5 ? bIm : aIm;
  }
#pragma unroll
  for (int r = 0; r < 4; ++r) { s.re[r] = nr[r]; s.im[r] = ni[r]; }
}

template <int NQ>
DEV void ansatz_f(Psi4& s, const float2* __restrict__ Mg, int lane) {
#pragma unroll
  for (int d = 0; d < 2; ++d) {
    const float2* Md = Mg + d * NQ * 4;
    pair_gate<0>(s, Md + 0, Md + 4, lane);
    pair_gate<2>(s, Md + 8, Md + 12, lane);
    pair_gate<4>(s, Md + 16, Md + 20, lane);
    if (NQ == 8) regpair_gate(s, Md + 24, Md + 28);
    else reg0_gate(s, Md + 24);
    perm_cx<NQ == 8>(s, lane);
  }
}

// Vsw layout (single-term, validated R10/R11): idx = k*16384 + g*512 + L*8 + jj
// g = w*8 + half*4 + t; half=0 re tiles, 1 im tiles; L = quad*16 + (n&15)
DEV void store_v(unsigned short* __restrict__ Vsw, int n, int kk, float v) {
  int k = kk >> 5, rem = kk & 31, quad = rem >> 3, jj = rem & 7;
  int nn = n & 255;
  int w = (nn >> 6) & 3, t = (nn >> 4) & 3, cl = nn & 15;
  int g = w * 8 + ((n >= 256) ? 4 + t : t);
  int L = quad * 16 + cl;
  size_t base = (size_t)k * 16384 + (size_t)g * 512 + (size_t)L * 8 + jj;
  Vsw[base] = f16b(v);
}

__global__ void build_u(const float* __restrict__ th1, const float* __restrict__ th2,
                        const float* __restrict__ th3, unsigned short* __restrict__ Vsw) {
  __shared__ float2 Mg[46 * 4];
  const int tid = threadIdx.x;
  if (tid < 46) {
    float thx, thy, thz;
    if (tid < 16)      { thx = th1[tid * 3]; thy = th1[tid * 3 + 1]; thz = th1[tid * 3 + 2]; }
    else if (tid < 30) { int u = (tid - 16) * 3; thx = th2[u]; thy = th2[u + 1]; thz = th2[u + 2]; }
    else               { int u = (tid - 30) * 3; thx = th3[u]; thy = th3[u + 1]; thz = th3[u + 2]; }
    float sx, cx_, sy, cy_, sz, cz_;
    sincosf(0.5f * thx, &sx, &cx_);
    sincosf(0.5f * thy, &sy, &cy_);
    sincosf(0.5f * thz, &sz, &cz_);
    float2 rx[4] = {{cx_, 0}, {0, -sx}, {0, -sx}, {cx_, 0}};
    float2 ry[4] = {{cy_, 0}, {-sy, 0}, {sy, 0}, {cy_, 0}};
    float2 A0 = cadd(cmul(ry[0], rx[0]), cmul(ry[1], rx[2]));
    float2 A1 = cadd(cmul(ry[0], rx[1]), cmul(ry[1], rx[3]));
    float2 A2 = cadd(cmul(ry[2], rx[0]), cmul(ry[3], rx[2]));
    float2 A3 = cadd(cmul(ry[2], rx[1]), cmul(ry[3], rx[3]));
    float2 ezm = make_float2(cz_, -sz), ezp = make_float2(cz_, sz);
    Mg[tid * 4 + 0] = cmul(ezm, A0);
    Mg[tid * 4 + 1] = cmul(ezm, A1);
    Mg[tid * 4 + 2] = cmul(ezp, A2);
    Mg[tid * 4 + 3] = cmul(ezp, A3);
  }
  __syncthreads();

  const int lane = tid & 63;
  const int j = blockIdx.x * 4 + (tid >> 6);
  Psi4 s;
#pragma unroll
  for (int r = 0; r < 4; ++r) {
    int a = (r << 6) | lane;
    s.re[r] = (a == j) ? 1.f : 0.f;
    s.im[r] = 0.f;
  }
  ansatz_f<8>(s, Mg, lane);
  ansatz_f<7>(s, Mg + 16 * 4, lane);
  ansatz_f<8>(s, Mg + 30 * 4, lane);
#pragma unroll
  for (int r = 0; r < 4; ++r) {
    int a = (r << 6) | lane;
    store_v(Vsw, a, j, s.re[r]);
    store_v(Vsw, a + 256, j, s.im[r]);
  }
}

// ---------------------------------------------------------------------------
// Kernel B: 1024 blocks x 256 threads (4 waves), 32 rows/block, 4 blocks/CU.
// Wave w (= ww) owns amp slice [w*64, w*64+64) with BOTH re (tt 0-3) and im
// (tt 4-7) tiles over mt=0..1 row-tiles -> acc = 2x8 f32x4 = 64 AGPR.
// A2 col slot swizzle (cc ^ 2*quad) on write AND read: conflict-free.
// ---------------------------------------------------------------------------

__global__ __launch_bounds__(256, 4) void pqc_main(const float* __restrict__ x,
                                                   const unsigned short* __restrict__ Vsw,
                                                   float* __restrict__ out) {
  const int tid = threadIdx.x;
  const int w = tid >> 6;       // wave = amp slice: i in [w*64, w*64+64)
  const int L = tid & 63;
  const int quad = L >> 4;
  const int c = L & 15;
  const int row0 = blockIdx.x * 32;

  // A2[k][mt][slot*8 + j], slot = quad*16 + (cc ^ 2*quad)  (f16, 16 KB)
  __shared__ unsigned short A2[8][2][512];
  __shared__ float ys[32][8];
  __shared__ float invn[32];
  float* part = (float*)&A2[0][0][0];        // overlay after k-loop (4 KB)

  // ---- stage A: 32 rows x 256 cols; R7 mapping, wave covers k in {w, w+4}.
  {
    const float4* xsrc = (const float4*)(x + (size_t)row0 * 256);
    const int r8 = L & 7;            // row within group of 8
    const int kf = L >> 3;           // fine col 0..7 within k-chunk
    const int q = kf >> 1;
    const int jj0 = (kf & 1) * 4;
#pragma unroll
    for (int ch2 = 0; ch2 < 2; ++ch2) {
      const int ch = w + ch2 * 4;    // k-chunk index (0..7)
#pragma unroll
      for (int i = 0; i < 4; ++i) {
        int row = i * 8 + r8;
        float4 f = xsrc[row * 64 + ch * 8 + kf];
        ushort4 h;
        h.x = f16b(f.x); h.y = f16b(f.y); h.z = f16b(f.z); h.w = f16b(f.w);
        int mt = row >> 4, cc = row & 15;
        int idx = (q * 16 + (cc ^ (q << 1))) * 8 + jj0;
        *(ushort4*)&A2[ch][mt][idx] = h;
      }
    }
  }
  __syncthreads();

  // ---- MFMA K-loop (single term f16): wave covers tt=0..7 of its w-slice
  f32x4 acc[2][8];
#pragma unroll
  for (int mt = 0; mt < 2; ++mt)
#pragma unroll
    for (int tt = 0; tt < 8; ++tt) acc[mt][tt] = (f32x4){0.f, 0.f, 0.f, 0.f};

  const unsigned short* pb = Vsw + (size_t)w * 4096 + (size_t)L * 8;
  const int sL8 = (quad * 16 + (c ^ (quad << 1))) * 8;   // swizzled A slot

#pragma unroll 1   // cap unroll: keep regs in budget
  for (int k = 0; k < 8; ++k) {
    half8 ah0 = *(const half8*)&A2[k][0][sL8];
    half8 ah1 = *(const half8*)&A2[k][1][sL8];
    const unsigned short* pk = pb + (size_t)k * 16384;
#pragma unroll
    for (int tt = 0; tt < 8; ++tt) {
      half8 bh = *(const half8*)(pk + tt * 512);
      acc[0][tt] = __builtin_amdgcn_mfma_f32_16x16x32_f16(ah0, bh, acc[0][tt], 0, 0, 0);
      acc[1][tt] = __builtin_amdgcn_mfma_f32_16x16x32_f16(ah1, bh, acc[1][tt], 0, 0, 0);
    }
  }
  __syncthreads();   // A2 dead; part overlay becomes valid

  // ---- epilogue: probs (re^2+im^2, both in-wave) -> signed Walsh via DPP.
  // D layout: row m = mt*16 + quad*4 + r, col = c; tile tt<4 = re of amp
  // i = w*64 + tt*16 + c; tile tt+4 = im of same i.
  const int m1 = (c & 1) << 31;
  const int m2 = (c & 2) << 30;
  const int m4 = (c & 4) << 29;
  const int m8 = (c & 8) << 28;
#pragma unroll
  for (int mt = 0; mt < 2; ++mt) {
#pragma unroll
    for (int r = 0; r < 4; ++r) {
      float p0 = acc[mt][0][r] * acc[mt][0][r] + acc[mt][4][r] * acc[mt][4][r];
      float p1 = acc[mt][1][r] * acc[mt][1][r] + acc[mt][5][r] * acc[mt][5][r];
      float p2 = acc[mt][2][r] * acc[mt][2][r] + acc[mt][6][r] * acc[mt][6][r];
      float p3 = acc[mt][3][r] * acc[mt][3][r] + acc[mt][7][r] * acc[mt][7][r];
      float s01 = p0 + p1, s23 = p2 + p3;
      float av = s01 + s23;               // -> j=0,1,4..7
      float bv = s01 - s23;               // sign bit5 (tt>>1) -> j=2
      float cv = (p0 - p1) + (p2 - p3);   // sign bit4 (tt&1) -> j=3
      av = px1(av) + fsgn(av, m1);
      bv += px1(bv);  cv += px1(cv);
      av = px2(av) + fsgn(av, m2);
      bv += px2(bv);  cv += px2(cv);
      av = px4(av) + fsgn(av, m4);
      bv += px4(bv);  cv += px4(cv);
      av = px8(av) + fsgn(av, m8);
      bv += px8(bv);  cv += px8(cv);
      int m = mt * 16 + quad * 4 + r;
      float* pm = part + (w * 32 + m) * 8;
      if (c == 0) {
        pm[0] = ((w >> 1) & 1) ? -av : av;  // j=0: bit7(i)
        pm[1] = (w & 1) ? -av : av;         // j=1: bit6(i)
        pm[2] = bv;
        pm[3] = cv;
      } else if (c == 8) pm[4] = av;   // j=4: bit3
      else if (c == 4) pm[5] = av;     // j=5: bit2
      else if (c == 2) pm[6] = av;     // j=6: bit1
      else if (c == 1) pm[7] = av;     // j=7: bit0
    }
  }
  __syncthreads();

  {  // ys + row-norm in ONE phase: jj in 8 consecutive lanes -> DPP reduce
    int m = tid >> 3, jj = tid & 7;
    float acc_y = part[(0 * 32 + m) * 8 + jj] + part[(1 * 32 + m) * 8 + jj]
                + part[(2 * 32 + m) * 8 + jj] + part[(3 * 32 + m) * 8 + jj];
    ys[m][jj] = acc_y;
    float sq = acc_y * acc_y;
    sq += px1(sq);
    sq += px2(sq);
    sq += px4(sq);          // all 8 lanes of the jj-group hold sum_j y_j^2
    if (jj == 0) invn[m] = (sq == 0.f) ? 0.f : 1.f / sqrtf(sq);
  }
  __syncthreads();

  // ---- write out: 32 rows x 64 float4 = 2048 float4, 8 per thread
  float4* o4 = (float4*)(out + (size_t)row0 * 256);
#pragma unroll
  for (int i = 0; i < 8; ++i) {
    int e = i * 256 + tid;
    int row = e >> 6;
    int c4 = (e & 63) * 4;
    float4 v = make_float4(0.f, 0.f, 0.f, 0.f);
    if (c4 < 8) {
      float iv = invn[row];
      float t0 = ys[row][c4 + 0] * iv;
      float t1 = ys[row][c4 + 1] * iv;
      float t2 = ys[row][c4 + 2] * iv;
      float t3 = ys[row][c4 + 3] * iv;
      v = make_float4(t0 * t0, t1 * t1, t2 * t2, t3 * t3);
    }
    o4[e] = v;
  }
}

extern "C" void kernel_launch(void* const* d_in, const int* in_sizes, int n_in,
                              void* d_out, int out_size, void* d_ws, size_t ws_size,
                              hipStream_t stream) {
  const float* x = (const float*)d_in[0];
  const float* th1 = (const float*)d_in[1];
  const float* th2 = (const float*)d_in[2];
  const float* th3 = (const float*)d_in[3];
  float* out = (float*)d_out;
  unsigned short* Vsw = (unsigned short*)d_ws;  // 256 KB swizzled V (f16)

  build_u<<<64, 256, 0, stream>>>(th1, th2, th3, Vsw);
  pqc_main<<<1024, 256, 0, stream>>>(x, Vsw, out);
}

// Round 13
// 109.105 us; speedup vs baseline: 1.0002x; 1.0002x over previous
//
#include <hip/hip_runtime.h>
#include <math.h>

// PQC autoencoder. out = g(U x), U = fixed 256x256 unitary from thetas
// (input normalization cancels: y/||y|| scale-invariant in x).
// Kernel A (build_u): blocks 0..63 = fused-gate statevector sim -> V (f16,
//   MFMA-B-fragment stream order, validated R10-R12); blocks 64..2111 =
//   grid-stride ZERO-FILL of out (31.7 MB of out is constant zeros; fills
//   measured at ~80% HBM peak vs ~19% for in-kernel epilogue writes).
// Kernel B (pqc_main): single-term f16 MFMA GEMM (32768 x 512 x 256),
//   R11 shape (64 rows/block, 512 thr, 2 blocks/CU, B-ring, DPP Walsh).
//   R13: writes ONLY the 8 nonzero floats/row (1 store/thread, in-register
//   DPP norm) -- WRITE 32768 KB -> 1024 KB, no ys/invn LDS, one barrier fewer.

#define DEV __device__ __forceinline__

typedef __attribute__((ext_vector_type(8))) _Float16 half8;  // 8 f16 = 4 VGPR
typedef __attribute__((ext_vector_type(4))) float f32x4;

DEV float2 cmul(float2 a, float2 b) {
  return make_float2(a.x * b.x - a.y * b.y, a.x * b.y + a.y * b.x);
}
DEV float2 cadd(float2 a, float2 b) { return make_float2(a.x + b.x, a.y + b.y); }

DEV unsigned short f16b(float v) {
  _Float16 h = (_Float16)v;                    // RNE convert
  return __builtin_bit_cast(unsigned short, h);
}

// ---- DPP cross-lane (VALU pipe, rows of 16) ------------------------------
template <int CTRL>
DEV float dppf(float v) {
  return __int_as_float(__builtin_amdgcn_mov_dpp(__float_as_int(v), CTRL, 0xF, 0xF, true));
}
DEV float px1(float v) { return dppf<0xB1>(v); }                  // lane^1
DEV float px2(float v) { return dppf<0x4E>(v); }                  // lane^2
DEV float px4(float v) { return dppf<0x1B>(dppf<0x141>(v)); }     // ^7 then ^3 = ^4
DEV float px8(float v) { return dppf<0x141>(dppf<0x140>(v)); }    // ^15 then ^7 = ^8
DEV float fsgn(float v, int m) { return __int_as_float(__float_as_int(v) ^ m); }

// ---------------------------------------------------------------------------
// Kernel A (gate math unchanged, validated R2-R12) + fused out-zero-fill
// ---------------------------------------------------------------------------

struct Psi4 { float re[4]; float im[4]; };
// amplitude a = (r<<6)|lane; bit q of a: q<6 -> lane bit q; q==6 -> r&1; q==7 -> r>>1

template <int Q>
DEV void pair_gate(Psi4& s, const float2* __restrict__ Mlo,
                   const float2* __restrict__ Mhi, int lane) {
  const int b0 = (lane >> Q) & 1, b1 = (lane >> (Q + 1)) & 1;
  float2 lo_d = Mlo[b0 * 2 + b0];
  float2 lo_o = Mlo[b0 * 2 + (b0 ^ 1)];
  float2 hi_d = Mhi[b1 * 2 + b1];
  float2 hi_o = Mhi[b1 * 2 + (b1 ^ 1)];
  float2 c00 = cmul(hi_d, lo_d);
  float2 c01 = cmul(hi_d, lo_o);
  float2 c10 = cmul(hi_o, lo_d);
  float2 c11 = cmul(hi_o, lo_o);
  const int m0 = 1 << Q, m1 = 2 << Q;
#pragma unroll
  for (int r = 0; r < 4; ++r) {
    float ar = s.re[r], ai = s.im[r];
    float p0r = __shfl_xor(ar, m0, 64), p0i = __shfl_xor(ai, m0, 64);
    float p1r = __shfl_xor(ar, m1, 64), p1i = __shfl_xor(ai, m1, 64);
    float p2r = __shfl_xor(ar, m0 | m1, 64), p2i = __shfl_xor(ai, m0 | m1, 64);
    float nr = c00.x * ar - c00.y * ai + c01.x * p0r - c01.y * p0i
             + c10.x * p1r - c10.y * p1i + c11.x * p2r - c11.y * p2i;
    float ni = c00.x * ai + c00.y * ar + c01.x * p0i + c01.y * p0r
             + c10.x * p1i + c10.y * p1r + c11.x * p2i + c11.y * p2r;
    s.re[r] = nr; s.im[r] = ni;
  }
}

DEV void regpair_gate(Psi4& s, const float2* __restrict__ Mlo,
                      const float2* __restrict__ Mhi) {
  float nr[4], ni[4];
#pragma unroll
  for (int r = 0; r < 4; ++r) {
    const int b0 = r & 1, b1 = (r >> 1) & 1;
    float2 c00 = cmul(Mhi[b1 * 2 + b1], Mlo[b0 * 2 + b0]);
    float2 c01 = cmul(Mhi[b1 * 2 + b1], Mlo[b0 * 2 + (b0 ^ 1)]);
    float2 c10 = cmul(Mhi[b1 * 2 + (b1 ^ 1)], Mlo[b0 * 2 + b0]);
    float2 c11 = cmul(Mhi[b1 * 2 + (b1 ^ 1)], Mlo[b0 * 2 + (b0 ^ 1)]);
    nr[r] = c00.x * s.re[r] - c00.y * s.im[r]
          + c01.x * s.re[r ^ 1] - c01.y * s.im[r ^ 1]
          + c10.x * s.re[r ^ 2] - c10.y * s.im[r ^ 2]
          + c11.x * s.re[r ^ 3] - c11.y * s.im[r ^ 3];
    ni[r] = c00.x * s.im[r] + c00.y * s.re[r]
          + c01.x * s.im[r ^ 1] + c01.y * s.re[r ^ 1]
          + c10.x * s.im[r ^ 2] + c10.y * s.re[r ^ 2]
          + c11.x * s.im[r ^ 3] + c11.y * s.re[r ^ 3];
  }
#pragma unroll
  for (int r = 0; r < 4; ++r) { s.re[r] = nr[r]; s.im[r] = ni[r]; }
}

DEV void reg0_gate(Psi4& s, const float2* __restrict__ M) {
  float nr[4], ni[4];
#pragma unroll
  for (int r = 0; r < 4; ++r) {
    const int b = r & 1;
    float2 d = M[b * 2 + b], o = M[b * 2 + (b ^ 1)];
    nr[r] = d.x * s.re[r] - d.y * s.im[r] + o.x * s.re[r ^ 1] - o.y * s.im[r ^ 1];
    ni[r] = d.x * s.im[r] + d.y * s.re[r] + o.x * s.im[r ^ 1] + o.y * s.re[r ^ 1];
  }
#pragma unroll
  for (int r = 0; r < 4; ++r) { s.re[r] = nr[r]; s.im[r] = ni[r]; }
}

template <bool FULL8>
DEV void perm_cx(Psi4& s, int lane) {
  const int slane = (lane ^ (lane << 1)) & 63;
  const bool L5 = ((lane >> 5) & 1) != 0;
  float nr[4], ni[4];
#pragma unroll
  for (int r = 0; r < 4; ++r) {
    const int r0 = r & 1, r1 = (r >> 1) & 1;
    const int hiBit = FULL8 ? (r1 ^ r0) : r1;
    const int sA = (hiBit << 1) | r0;
    const int sB = sA ^ 1;
    float aRe = __shfl(s.re[sA], slane, 64);
    float aIm = __shfl(s.im[sA], slane, 64);
    float bRe = __shfl(s.re[sB], slane, 64);
    float bIm = __shfl(s.im[sB], slane, 64);
    nr[r] = L5 ? bRe : aRe;
    ni[r] = L5 ? bIm : aIm;
  }
#pragma unroll
  for (int r = 0; r < 4; ++r) { s.re[r] = nr[r]; s.im[r] = ni[r]; }
}

template <int NQ>
DEV void ansatz_f(Psi4& s, const float2* __restrict__ Mg, int lane) {
#pragma unroll
  for (int d = 0; d < 2; ++d) {
    const float2* Md = Mg + d * NQ * 4;
    pair_gate<0>(s, Md + 0, Md + 4, lane);
    pair_gate<2>(s, Md + 8, Md + 12, lane);
    pair_gate<4>(s, Md + 16, Md + 20, lane);
    if (NQ == 8) regpair_gate(s, Md + 24, Md + 28);
    else reg0_gate(s, Md + 24);
    perm_cx<NQ == 8>(s, lane);
  }
}

// Vsw layout (single-term, validated R10-R12): idx = k*16384 + g*512 + L*8 + jj
// g = w*8 + half*4 + t; half=0 re tiles, 1 im tiles; L = quad*16 + (n&15)
DEV void store_v(unsigned short* __restrict__ Vsw, int n, int kk, float v) {
  int k = kk >> 5, rem = kk & 31, quad = rem >> 3, jj = rem & 7;
  int nn = n & 255;
  int w = (nn >> 6) & 3, t = (nn >> 4) & 3, cl = nn & 15;
  int g = w * 8 + ((n >= 256) ? 4 + t : t);
  int L = quad * 16 + cl;
  size_t base = (size_t)k * 16384 + (size_t)g * 512 + (size_t)L * 8 + jj;
  Vsw[base] = f16b(v);
}

__global__ void build_u(const float* __restrict__ th1, const float* __restrict__ th2,
                        const float* __restrict__ th3, unsigned short* __restrict__ Vsw,
                        float4* __restrict__ ofill) {
  // Blocks 64..2111: zero-fill out (2048 blocks x 256 thr x 4 float4 = 32 MB)
  if (blockIdx.x >= 64) {
    size_t i = (size_t)(blockIdx.x - 64) * 256 + threadIdx.x;
    float4 z = make_float4(0.f, 0.f, 0.f, 0.f);
#pragma unroll
    for (int r = 0; r < 4; ++r) ofill[i + (size_t)r * 524288] = z;
    return;
  }
  // Blocks 0..63: statevector sim, one basis column per wave.
  __shared__ float2 Mg[46 * 4];
  const int tid = threadIdx.x;
  if (tid < 46) {
    float thx, thy, thz;
    if (tid < 16)      { thx = th1[tid * 3]; thy = th1[tid * 3 + 1]; thz = th1[tid * 3 + 2]; }
    else if (tid < 30) { int u = (tid - 16) * 3; thx = th2[u]; thy = th2[u + 1]; thz = th2[u + 2]; }
    else               { int u = (tid - 30) * 3; thx = th3[u]; thy = th3[u + 1]; thz = th3[u + 2]; }
    float sx, cx_, sy, cy_, sz, cz_;
    sincosf(0.5f * thx, &sx, &cx_);
    sincosf(0.5f * thy, &sy, &cy_);
    sincosf(0.5f * thz, &sz, &cz_);
    float2 rx[4] = {{cx_, 0}, {0, -sx}, {0, -sx}, {cx_, 0}};
    float2 ry[4] = {{cy_, 0}, {-sy, 0}, {sy, 0}, {cy_, 0}};
    float2 A0 = cadd(cmul(ry[0], rx[0]), cmul(ry[1], rx[2]));
    float2 A1 = cadd(cmul(ry[0], rx[1]), cmul(ry[1], rx[3]));
    float2 A2 = cadd(cmul(ry[2], rx[0]), cmul(ry[3], rx[2]));
    float2 A3 = cadd(cmul(ry[2], rx[1]), cmul(ry[3], rx[3]));
    float2 ezm = make_float2(cz_, -sz), ezp = make_float2(cz_, sz);
    Mg[tid * 4 + 0] = cmul(ezm, A0);
    Mg[tid * 4 + 1] = cmul(ezm, A1);
    Mg[tid * 4 + 2] = cmul(ezp, A2);
    Mg[tid * 4 + 3] = cmul(ezp, A3);
  }
  __syncthreads();

  const int lane = tid & 63;
  const int j = blockIdx.x * 4 + (tid >> 6);
  Psi4 s;
#pragma unroll
  for (int r = 0; r < 4; ++r) {
    int a = (r << 6) | lane;
    s.re[r] = (a == j) ? 1.f : 0.f;
    s.im[r] = 0.f;
  }
  ansatz_f<8>(s, Mg, lane);
  ansatz_f<7>(s, Mg + 16 * 4, lane);
  ansatz_f<8>(s, Mg + 30 * 4, lane);
#pragma unroll
  for (int r = 0; r < 4; ++r) {
    int a = (r << 6) | lane;
    store_v(Vsw, a, j, s.re[r]);
    store_v(Vsw, a + 256, j, s.im[r]);
  }
}

// ---------------------------------------------------------------------------
// Kernel B: 512 blocks x 512 threads (8 waves), 64 rows/block, 2 blocks/CU.
// Wave ww: w = ww>>1 (amp slice), half = ww&1 (re|im tiles), n=64 cols/wave;
// mt = 4 row-tiles -> acc = 4x4 f32x4 = 64 AGPR. Single term f16; B 2-deep
// ring (R11). Final write: ONLY cols 0..7 per row (zeros pre-filled).
// ---------------------------------------------------------------------------

__global__ __launch_bounds__(512, 4) void pqc_main(const float* __restrict__ x,
                                                   const unsigned short* __restrict__ Vsw,
                                                   float* __restrict__ out) {
  const int tid = threadIdx.x;
  const int ww = tid >> 6;
  const int w = ww >> 1;        // amp slice: i in [w*64, w*64+64)
  const int half = ww & 1;      // 0 = re tiles, 1 = im tiles
  const int L = tid & 63;
  const int quad = L >> 4;
  const int c = L & 15;
  const int row0 = blockIdx.x * 64;

  // A2[k][mt][slot*8 + j], slot = quad*16 + (cc ^ 2*quad)  (f16, 32 KB)
  __shared__ unsigned short A2[8][4][512];
  float* part = (float*)&A2[0][0][0];        // overlay after k-loop (16 KB)

  const unsigned short* pb = Vsw + (size_t)w * 4096 + (size_t)half * 2048 + (size_t)L * 8;

  // B prefetch for k=0 (independent of LDS staging; latency hides under it)
  half8 b0 = *(const half8*)(pb);
  half8 b1 = *(const half8*)(pb + 512);

  // ---- stage A: 64 rows x 256 cols; lane covers 8 rows (r8) x wave k-group.
  {
    const float4* xsrc = (const float4*)(x + (size_t)row0 * 256);
    const int r8 = L & 7;            // row within group of 8
    const int kf = L >> 3;           // fine col 0..7 within wave's k-group
    const int q = kf >> 1;
    const int jj0 = (kf & 1) * 4;
#pragma unroll
    for (int i = 0; i < 8; ++i) {
      int row = i * 8 + r8;
      float4 f = xsrc[row * 64 + ww * 8 + kf];
      ushort4 h;
      h.x = f16b(f.x); h.y = f16b(f.y); h.z = f16b(f.z); h.w = f16b(f.w);
      int mt = row >> 4, cc = row & 15;
      int idx = (q * 16 + (cc ^ (q << 1))) * 8 + jj0;
      *(ushort4*)&A2[ww][mt][idx] = h;
    }
  }
  __syncthreads();

  // ---- MFMA K-loop (single term, 2-deep B ring)
  f32x4 acc[4][4];
#pragma unroll
  for (int mt = 0; mt < 4; ++mt)
#pragma unroll
    for (int tt = 0; tt < 4; ++tt) acc[mt][tt] = (f32x4){0.f, 0.f, 0.f, 0.f};

  const int sL8 = (quad * 16 + (c ^ (quad << 1))) * 8;   // swizzled A slot

#pragma unroll 1   // cap unroll: pipeline 1 k-iter deep, keep regs in budget
  for (int k = 0; k < 8; ++k) {
    half8 ah[4];
#pragma unroll
    for (int mt = 0; mt < 4; ++mt)
      ah[mt] = *(const half8*)&A2[k][mt][sL8];
    const unsigned short* pk = pb + (size_t)k * 16384;
    const unsigned short* pn = pb + (size_t)((k < 7) ? k + 1 : k) * 16384;

    half8 b2 = *(const half8*)(pk + 2 * 512);
#pragma unroll
    for (int mt = 0; mt < 4; ++mt)
      acc[mt][0] = __builtin_amdgcn_mfma_f32_16x16x32_f16(ah[mt], b0, acc[mt][0], 0, 0, 0);
    half8 b3 = *(const half8*)(pk + 3 * 512);
#pragma unroll
    for (int mt = 0; mt < 4; ++mt)
      acc[mt][1] = __builtin_amdgcn_mfma_f32_16x16x32_f16(ah[mt], b1, acc[mt][1], 0, 0, 0);
    b0 = *(const half8*)(pn);
#pragma unroll
    for (int mt = 0; mt < 4; ++mt)
      acc[mt][2] = __builtin_amdgcn_mfma_f32_16x16x32_f16(ah[mt], b2, acc[mt][2], 0, 0, 0);
    b1 = *(const half8*)(pn + 512);
#pragma unroll
    for (int mt = 0; mt < 4; ++mt)
      acc[mt][3] = __builtin_amdgcn_mfma_f32_16x16x32_f16(ah[mt], b3, acc[mt][3], 0, 0, 0);
  }
  __syncthreads();   // A2 dead; part overlay becomes valid

  // ---- epilogue: partial probs (re^2 or im^2) -> signed Walsh via DPP.
  // D layout: row m = mt*16 + quad*4 + r, col = c; tile tt covers amps
  // i = w*64 + tt*16 + c.
  const int m1 = (c & 1) << 31;
  const int m2 = (c & 2) << 30;
  const int m4 = (c & 4) << 29;
  const int m8 = (c & 8) << 28;
#pragma unroll
  for (int mt = 0; mt < 4; ++mt) {
#pragma unroll
    for (int r = 0; r < 4; ++r) {
      float p0 = acc[mt][0][r] * acc[mt][0][r];
      float p1 = acc[mt][1][r] * acc[mt][1][r];
      float p2 = acc[mt][2][r] * acc[mt][2][r];
      float p3 = acc[mt][3][r] * acc[mt][3][r];
      float s01 = p0 + p1, s23 = p2 + p3;
      float av = s01 + s23;               // -> j=0,1,4..7
      float bv = s01 - s23;               // sign bit5 (tt>>1) -> j=2
      float cv = (p0 - p1) + (p2 - p3);   // sign bit4 (tt&1) -> j=3
      av = px1(av) + fsgn(av, m1);
      bv += px1(bv);  cv += px1(cv);
      av = px2(av) + fsgn(av, m2);
      bv += px2(bv);  cv += px2(cv);
      av = px4(av) + fsgn(av, m4);
      bv += px4(bv);  cv += px4(cv);
      av = px8(av) + fsgn(av, m8);
      bv += px8(bv);  cv += px8(cv);
      int m = mt * 16 + quad * 4 + r;
      float* pm = part + (ww * 64 + m) * 8;
      if (c == 0) {
        pm[0] = ((w >> 1) & 1) ? -av : av;  // j=0: bit7(i)
        pm[1] = (w & 1) ? -av : av;         // j=1: bit6(i)
        pm[2] = bv;
        pm[3] = cv;
      } else if (c == 8) pm[4] = av;   // j=4: bit3
      else if (c == 4) pm[5] = av;     // j=5: bit2
      else if (c == 2) pm[6] = av;     // j=6: bit1
      else if (c == 1) pm[7] = av;     // j=7: bit0
    }
  }
  __syncthreads();

  {  // final: combine 8 partials, in-register DPP norm, write 8 floats/row.
    int m = tid >> 3, jj = tid & 7;
    float acc_y = 0.f;
#pragma unroll
    for (int p = 0; p < 8; ++p) acc_y += part[(p * 64 + m) * 8 + jj];
    float sq = acc_y * acc_y;
    sq += px1(sq);
    sq += px2(sq);
    sq += px4(sq);          // all 8 jj-lanes now hold sum_j y_j^2
    float iv = (sq == 0.f) ? 0.f : 1.f / sqrtf(sq);
    float t = acc_y * iv;
    out[(size_t)(row0 + m) * 256 + jj] = t * t;   // cols 8..255 pre-zeroed
  }
}

extern "C" void kernel_launch(void* const* d_in, const int* in_sizes, int n_in,
                              void* d_out, int out_size, void* d_ws, size_t ws_size,
                              hipStream_t stream) {
  const float* x = (const float*)d_in[0];
  const float* th1 = (const float*)d_in[1];
  const float* th2 = (const float*)d_in[2];
  const float* th3 = (const float*)d_in[3];
  float* out = (float*)d_out;
  unsigned short* Vsw = (unsigned short*)d_ws;  // 256 KB swizzled V (f16)

  // blocks 0..63: build V; blocks 64..2111: zero-fill out (stream-ordered
  // before pqc_main, which then writes only the 8 nonzero cols per row).
  build_u<<<2112, 256, 0, stream>>>(th1, th2, th3, Vsw, (float4*)out);
  pqc_main<<<512, 512, 0, stream>>>(x, Vsw, out);
}